// Round 9
// baseline (206.696 us; speedup 1.0000x reference)
//
#include <hip/hip_runtime.h>

// NRI MLP decoder, fused f16-MFMA pipeline, v26.
// B=4, T=64 (t<63 out), A=32, R=992 (=32 recv x 31 edges), D=64, S=4,
// E=4 (type 0 skipped), MH=MO=NH=256.
//
//   h1[b,t,r] = lrelu(PS[send(r)] + PRb[rec(r)])   (PRb has b1 folded, from ka)
//   msg = lrelu(h1 @ W2 + b2) ; agg[a] = sum_{r:rec=a} g[r]*msg[r]
// kb v26: m201-style 4-phase schedule at the 1-block/CU 256-reg operating
// point. Root cause from v18..v25: at 2 blocks/CU the 128-reg cap forbids
// operand double-buffering, so ds_reads execute AFTER each barrier and MFMA
// after the reads -> step time = SUM of pipe times (~3300cy), MfmaUtil 33%.
// The verified m201 mechanism (reads issued BEFORE the barrier, lgkmcnt(0)
// after -> LDS service overlaps the previous MFMA cluster) needs ping-pong
// af/bv register banks (+48 VGPR) -> only fits at (512,2) = 256 regs.
// Geometry: block = (e,bt,qq): M=256 rows x N=256 x K=256, grid 3024.
// 8 waves 2Mx4N, per-wave M=128/N=64, acc[8][4]=128 AGPR. LDS: h1F dbuf
// 32KB + Bt 3-slot ring 48KB + gs/b2s 2KB = 84KB -> 1 block/CU.
// Per K-step: 4 phases x {issue next ds_reads + role-op; s_barrier;
// lgkmcnt(0); setprio(1); 8 MFMA; setprio(0); s_barrier}. Roles: ph0 P(s+1)
// prefetch; ph1 gl16 Bt(s+2); ph2 counted vmcnt(2) + h1(s+1) build+ds_write;
// ph3 bv(s+1)+af01(s+1) reads. vmcnt(2) at ph2 drains gl16(s+1) (needed by
// ph3's bv reads; compiler can't track gl16->LDS deps) keeping gl16(s+2)
// in flight. Math/layouts identical to v18 (verified absmax 0.0625).

typedef _Float16 f16x8 __attribute__((ext_vector_type(8)));
typedef float f32x4 __attribute__((ext_vector_type(4)));
typedef unsigned short us16;

#define MFMAH(a, b, c) __builtin_amdgcn_mfma_f32_16x16x32_f16((a), (b), (c), 0, 0, 0)

// full-drain barrier (__syncthreads semantics, explicit) — prologue only
#define KBAR0() do {                                             \
  __builtin_amdgcn_sched_barrier(0);                             \
  asm volatile("s_waitcnt vmcnt(0) lgkmcnt(0)" ::: "memory");    \
  __builtin_amdgcn_s_barrier();                                  \
  __builtin_amdgcn_sched_barrier(0);                             \
} while (0)

// m201 phase top: barrier, then drain own ds_reads (issued pre-barrier)
#define PH_TOP() do {                                            \
  __builtin_amdgcn_sched_barrier(0);                             \
  __builtin_amdgcn_s_barrier();                                  \
  asm volatile("s_waitcnt lgkmcnt(0)" ::: "memory");             \
  __builtin_amdgcn_sched_barrier(0);                             \
} while (0)

// m201 phase end: plain barrier (publishes LDS writes drained at PH_TOP)
#define PH_END() do {                                            \
  __builtin_amdgcn_sched_barrier(0);                             \
  __builtin_amdgcn_s_barrier();                                  \
  __builtin_amdgcn_sched_barrier(0);                             \
} while (0)

__device__ __forceinline__ unsigned pkh(float lo, float hi) {
  auto h = __builtin_amdgcn_cvt_pkrtz(lo, hi);
  return __builtin_bit_cast(unsigned, h);
}
__device__ __forceinline__ unsigned short f2h(float f) {
  return __builtin_bit_cast(unsigned short, (_Float16)f);
}
__device__ __forceinline__ float lrelu(float x) { return x > 0.f ? x : 0.01f * x; }

__device__ __forceinline__ void gl16(const void* g, void* l) {
  __builtin_amdgcn_global_load_lds(
      (const __attribute__((address_space(1))) unsigned int*)(unsigned long long)g,
      (__attribute__((address_space(3))) unsigned int*)(unsigned int)(unsigned long long)l,
      16, 0, 0);
}

// ---------------- kernel W: weight transpose + f16 convert ----------------
// W2F fragment-linear: [e][kstep 0..7][ntile 0..15][lane 0..63][j 0..7]
//   n = ntile*16 + (lane&15), k = kstep*32 + (lane>>4)*8 + j.
__global__ __launch_bounds__(256) void kw(
    const float* __restrict__ w1, const float* __restrict__ w2,
    const float* __restrict__ o1, const float* __restrict__ o2, const float* __restrict__ o3,
    unsigned short* __restrict__ W1T, unsigned short* __restrict__ W2F,
    unsigned short* __restrict__ O1T, unsigned short* __restrict__ O2T,
    unsigned short* __restrict__ O3T) {
  int i = blockIdx.x * 256 + threadIdx.x;
  if (i < 98304) {
    int k = i & 63, n = (i >> 6) & 255, eh = i >> 14;
    int e = (eh >> 1) + 1, half = eh & 1;
    W1T[i] = f2h(w1[(e * 128 + half * 64 + k) * 256 + n]);
    return;
  }
  i -= 98304;
  if (i < 196608) {
    int j = i & 7, l = (i >> 3) & 63, t = (i >> 9) & 15, s = (i >> 13) & 7, e = i >> 16;
    int n = t * 16 + (l & 15);
    int k = s * 32 + (l >> 4) * 8 + j;
    W2F[i] = f2h(w2[(e + 1) * 65536 + k * 256 + n]);
    return;
  }
  i -= 196608;
  if (i < 81920) {
    int k = i % 320, n = i / 320;
    O1T[i] = f2h(o1[k * 256 + n]);
    return;
  }
  i -= 81920;
  if (i < 65536) {
    int k = i & 255, n = i >> 8;
    O2T[i] = f2h(o2[k * 256 + n]);
    return;
  }
  i -= 65536;
  {
    int k = i & 255, n = i >> 8;
    O3T[i] = f2h(o3[k * 64 + n]);
  }
}

// ---------------- kernel A: per-atom projections P + gates G ----------------
__global__ __launch_bounds__(256) void ka(
    const float* __restrict__ inputs, const float* __restrict__ state,
    const float* __restrict__ rel_type, const unsigned short* __restrict__ W1T,
    const float* __restrict__ b1g,
    unsigned short* __restrict__ P, float* __restrict__ G) {
  int t = blockIdx.x, b = blockIdx.y;
  int bt = b * 63 + t;
  int tid = threadIdx.x, lane = tid & 63, wid = tid >> 6;
  int waveM = wid & 1, waveN = wid >> 1;
  __shared__ __align__(16) _Float16 xa[32 * 72];
  __shared__ __align__(16) _Float16 Bt[256 * 72];
  __shared__ __align__(16) _Float16 Ps[32 * 256];
  __shared__ float ss[32][4];
  {
    int a = tid >> 3, d0 = (tid & 7) * 8;
    const float* src = inputs + (((b * 32 + a) * 64 + t) << 6) + d0;
    float4 v0 = *(const float4*)src;
    float4 v1 = *(const float4*)(src + 4);
    uint4 w;
    w.x = pkh(v0.x, v0.y); w.y = pkh(v0.z, v0.w);
    w.z = pkh(v1.x, v1.y); w.w = pkh(v1.z, v1.w);
    *(uint4*)&xa[a * 72 + d0] = w;
  }
  if (tid < 128) {
    int a = tid >> 2, s = tid & 3;
    ss[a][s] = state[((b * 32 + a) * 64 + t) * 4 + s];
  }
  __syncthreads();
  #pragma unroll
  for (int q = 0; q < 12; ++q) {
    int task = tid + q * 256;
    int e = task >> 10, rem = task & 1023, a = rem >> 5, k = rem & 31;
    float g = 0.f;
    if (k < 31) {
      int sA = k + (k >= a ? 1 : 0);
      int r = a * 31 + k;
      const float* rt = rel_type + (b * 992 + r) * 16 + (e + 1);
      g = rt[0] * ss[sA][0] + rt[4] * ss[sA][1] + rt[8] * ss[sA][2] + rt[12] * ss[sA][3];
    }
    G[(bt * 3 + e) * 1024 + a * 32 + k] = g;
  }
  for (int eh = 0; eh < 6; ++eh) {
    #pragma unroll
    for (int q = 0; q < 8; ++q) {
      int cid = tid + q * 256;
      int n = cid >> 3, c8 = (cid & 7) * 8;
      *(uint4*)&Bt[n * 72 + c8] = *(const uint4*)&W1T[(eh * 256 + n) * 64 + c8];
    }
    __syncthreads();
    f32x4 acc[8];
    #pragma unroll
    for (int f = 0; f < 8; ++f) acc[f] = f32x4{0.f, 0.f, 0.f, 0.f};
    #pragma unroll
    for (int ik = 0; ik < 2; ++ik) {
      int k0 = ik * 32;
      f16x8 av = *(const f16x8*)&xa[(waveM * 16 + (lane & 15)) * 72 + k0 + (lane >> 4) * 8];
      #pragma unroll
      for (int f = 0; f < 8; ++f) {
        f16x8 bv = *(const f16x8*)&Bt[(waveN * 128 + f * 16 + (lane & 15)) * 72 + k0 + (lane >> 4) * 8];
        acc[f] = MFMAH(av, bv, acc[f]);
      }
    }
    #pragma unroll
    for (int f = 0; f < 8; ++f) {
      int c = waveN * 128 + f * 16 + (lane & 15);
      float bias = (eh & 1) ? b1g[((eh >> 1) + 1) * 256 + c] : 0.f;
      #pragma unroll
      for (int i = 0; i < 4; ++i) {
        int rrow = waveM * 16 + (lane >> 4) * 4 + i;
        Ps[rrow * 256 + c] = (_Float16)(acc[f][i] + bias);
      }
    }
    __syncthreads();
    unsigned short* dst = P + (bt * 6 + eh) * 8192;
    #pragma unroll
    for (int q = 0; q < 4; ++q) {
      int o = (tid + q * 256) * 8;
      *(uint4*)&dst[o] = *(const uint4*)&Ps[o];
    }
    __syncthreads();
  }
}

// ---------------- kernel B v26: M256xN256 block, 4-phase m201 schedule ------
// grid.x = 3024 = 8*378; swz: (bt,qq) fastest, then e.
__global__ __launch_bounds__(512, 2) void kb(
    const unsigned short* __restrict__ P, const float* __restrict__ G,
    const unsigned short* __restrict__ W2F, const float* __restrict__ b2g,
    unsigned short* __restrict__ AGG3) {
  int bx = blockIdx.x;
  int swz = (bx & 7) * 378 + (bx >> 3);
  int e = swz / 1008;
  int rem = swz - e * 1008;
  int bt = rem >> 2, qq = rem & 3;           // qq: M-chunk of 256 rows (8 atoms)
  int tid = threadIdx.x, lane = tid & 63, wid = tid >> 6;
  int waveM = wid & 1, waveN = wid >> 1;     // 2M x 4N; per-wave M=128, N=64
  int lane15 = lane & 15, kqh = lane >> 4;   // 0..3

  __shared__ __align__(16) _Float16 h1F[2][8192];  // 2 x 16KB: 16 Mtiles frag-linear
  __shared__ __align__(16) _Float16 BtR[3][8192];  // 3 x 16KB ring
  __shared__ float gs[256];
  __shared__ float b2s[256];
  // LDS total: 32768 + 49152 + 1024 + 1024 = 83968B -> 1 block/CU.

  const unsigned short* psrc  = P + (bt * 6 + e * 2) * 8192;  // PS slab (send)
  const unsigned short* prsrc = psrc + 8192;                   // PRb slab
  const unsigned short* w2f   = W2F + e * 65536;               // [step][ntile][lane][8]

  // h1 build: thread owns slots tid (Mtile wid) and tid+512 (Mtile 8+wid).
  // slot -> row = mtile*16 + lane15, k-chunk kqh. Lane-linear writes.
  int k1  = (wid & 1) * 16 + lane15;          // k-slot (same for both Mtiles)
  int at1 = qq * 8 + (wid >> 1);              // full atom id, slot 1
  int at2 = at1 + 4;                          // slot 2
  int bs1 = (k1 < 31) ? (k1 + (k1 >= at1 ? 1 : 0)) : 0;  // k=31 pad (g=0)
  int bs2 = (k1 < 31) ? (k1 + (k1 >= at2 ? 1 : 0)) : 0;
  const unsigned short* pv1g = psrc + bs1 * 256 + kqh * 8;
  const unsigned short* pv2g = psrc + bs2 * 256 + kqh * 8;
  const unsigned short* rv1g = prsrc + at1 * 256 + kqh * 8;
  const unsigned short* rv2g = prsrc + at2 * 256 + kqh * 8;
  int wo1 = tid * 8, wo2 = (tid + 512) * 8;   // h1F element offsets

  // ---- prologue: P(0); stage Bt slots 0,1; gs/b2s; build h1(0) ----
  {
    f16x8 p1 = *(const f16x8*)pv1g;
    f16x8 p2 = *(const f16x8*)pv2g;
    f16x8 r1 = *(const f16x8*)rv1g;
    f16x8 r2 = *(const f16x8*)rv2g;
    __builtin_amdgcn_sched_barrier(0);
    #pragma unroll
    for (int j = 0; j < 2; ++j) {
      int c = j * 512 + tid;
      gl16(w2f + c * 8, (char*)&BtR[0][0] + c * 16);
      gl16(w2f + 8192 + c * 8, (char*)&BtR[1][0] + c * 16);
    }
    if (tid < 256) gs[tid] = G[((bt * 3 + e) << 10) + qq * 256 + tid];
    else b2s[tid - 256] = b2g[(e + 1) * 256 + (tid - 256)];
    f16x8 h = p1 + r1;
    *(f16x8*)&h1F[0][wo1] = __builtin_elementwise_max(h, h * (_Float16)0.01f);
    h = p2 + r2;
    *(f16x8*)&h1F[0][wo2] = __builtin_elementwise_max(h, h * (_Float16)0.01f);
  }
  KBAR0();  // Bt[0],Bt[1] + h1(0) + gs/b2s ready (full drain, once)

  f32x4 acc[8][4];
  #pragma unroll
  for (int f = 0; f < 8; ++f)
    #pragma unroll
    for (int g2 = 0; g2 < 4; ++g2) acc[f][g2] = f32x4{0.f, 0.f, 0.f, 0.f};

  // operand banks: bvp[s&1], afp[phase parity] — all indices compile-time.
  f16x8 bvp[2][4], afp[2][2];
  f16x8 pw1, pw2, rw1, rw2;  // P prefetch regs (loaded ph0, used ph2)

  // pre-reads for step 0 phase 0 (waited at its PH_TOP)
  #pragma unroll
  for (int g2 = 0; g2 < 4; ++g2)
    bvp[0][g2] = *(const f16x8*)&BtR[0][(waveN * 4 + g2) * 512 + lane * 8];
  afp[0][0] = *(const f16x8*)&h1F[0][(waveM * 8 + 0) * 512 + lane * 8];
  afp[0][1] = *(const f16x8*)&h1F[0][(waveM * 8 + 1) * 512 + lane * 8];

  #pragma unroll
  for (int s = 0; s < 8; ++s) {
    const int cb = s & 1, nb = cb ^ 1;

    // ---- phase 0: read af23(s); issue P(s+1) ----
    afp[1][0] = *(const f16x8*)&h1F[cb][(waveM * 8 + 2) * 512 + lane * 8];
    afp[1][1] = *(const f16x8*)&h1F[cb][(waveM * 8 + 3) * 512 + lane * 8];
    if (s < 7) {
      pw1 = *(const f16x8*)(pv1g + (s + 1) * 32);
      pw2 = *(const f16x8*)(pv2g + (s + 1) * 32);
      rw1 = *(const f16x8*)(rv1g + (s + 1) * 32);
      rw2 = *(const f16x8*)(rv2g + (s + 1) * 32);
    }
    PH_TOP();
    __builtin_amdgcn_s_setprio(1);
    #pragma unroll
    for (int g2 = 0; g2 < 4; ++g2) {
      acc[0][g2] = MFMAH(afp[0][0], bvp[cb][g2], acc[0][g2]);
      acc[1][g2] = MFMAH(afp[0][1], bvp[cb][g2], acc[1][g2]);
    }
    __builtin_amdgcn_s_setprio(0);
    PH_END();

    // ---- phase 1: read af45(s); issue gl16 Bt(s+2) ----
    afp[0][0] = *(const f16x8*)&h1F[cb][(waveM * 8 + 4) * 512 + lane * 8];
    afp[0][1] = *(const f16x8*)&h1F[cb][(waveM * 8 + 5) * 512 + lane * 8];
    if (s < 6) {
      #pragma unroll
      for (int j = 0; j < 2; ++j) {
        int c = j * 512 + tid;
        gl16(w2f + (s + 2) * 8192 + c * 8, (char*)&BtR[(s + 2) % 3][0] + c * 16);
      }
    }
    PH_TOP();
    __builtin_amdgcn_s_setprio(1);
    #pragma unroll
    for (int g2 = 0; g2 < 4; ++g2) {
      acc[2][g2] = MFMAH(afp[1][0], bvp[cb][g2], acc[2][g2]);
      acc[3][g2] = MFMAH(afp[1][1], bvp[cb][g2], acc[3][g2]);
    }
    __builtin_amdgcn_s_setprio(0);
    PH_END();

    // ---- phase 2: read af67(s); counted vmcnt; build h1(s+1) ----
    afp[1][0] = *(const f16x8*)&h1F[cb][(waveM * 8 + 6) * 512 + lane * 8];
    afp[1][1] = *(const f16x8*)&h1F[cb][(waveM * 8 + 7) * 512 + lane * 8];
    if (s < 7) {
      // drain P(s+1) AND gl16(s+1) (needed by ph3's bv reads); keep gl16(s+2)
      if (s < 6) asm volatile("s_waitcnt vmcnt(2)" ::: "memory");
      else       asm volatile("s_waitcnt vmcnt(0)" ::: "memory");
      f16x8 h = pw1 + rw1;
      *(f16x8*)&h1F[nb][wo1] = __builtin_elementwise_max(h, h * (_Float16)0.01f);
      h = pw2 + rw2;
      *(f16x8*)&h1F[nb][wo2] = __builtin_elementwise_max(h, h * (_Float16)0.01f);
    }
    PH_TOP();
    __builtin_amdgcn_s_setprio(1);
    #pragma unroll
    for (int g2 = 0; g2 < 4; ++g2) {
      acc[4][g2] = MFMAH(afp[0][0], bvp[cb][g2], acc[4][g2]);
      acc[5][g2] = MFMAH(afp[0][1], bvp[cb][g2], acc[5][g2]);
    }
    __builtin_amdgcn_s_setprio(0);
    PH_END();  // publishes h1(s+1) writes (drained at this phase's PH_TOP)

    // ---- phase 3: read bv(s+1) + af01(s+1) ----
    if (s < 7) {
      #pragma unroll
      for (int g2 = 0; g2 < 4; ++g2)
        bvp[nb][g2] = *(const f16x8*)&BtR[(s + 1) % 3][(waveN * 4 + g2) * 512 + lane * 8];
      afp[0][0] = *(const f16x8*)&h1F[nb][(waveM * 8 + 0) * 512 + lane * 8];
      afp[0][1] = *(const f16x8*)&h1F[nb][(waveM * 8 + 1) * 512 + lane * 8];
    }
    PH_TOP();
    __builtin_amdgcn_s_setprio(1);
    #pragma unroll
    for (int g2 = 0; g2 < 4; ++g2) {
      acc[6][g2] = MFMAH(afp[1][0], bvp[cb][g2], acc[6][g2]);
      acc[7][g2] = MFMAH(afp[1][1], bvp[cb][g2], acc[7][g2]);
    }
    __builtin_amdgcn_s_setprio(0);
    if (s < 7) PH_END();
  }

  // epilogue: p(at,c) = sum_k g[at*32+k]*lrelu(acc+b2); f16 partial per type.
  // Mtile f -> atom waveM*4+(f>>1); k = (f&1)*16 + kqh*4 + i.
  _Float16* aggh = (_Float16*)AGG3;
  #pragma unroll
  for (int ai = 0; ai < 4; ++ai) {
    int at = qq * 8 + waveM * 4 + ai;  // full atom id
    #pragma unroll
    for (int g2 = 0; g2 < 4; ++g2) {
      int c = (waveN * 4 + g2) * 16 + lane15;
      float bb = b2s[c];
      float p = 0.f;
      #pragma unroll
      for (int half = 0; half < 2; ++half) {
        int f = ai * 2 + half;
        int k4 = half * 16 + kqh * 4;
        #pragma unroll
        for (int i = 0; i < 4; ++i)
          p += gs[(waveM * 4 + ai) * 32 + k4 + i] * lrelu(acc[f][g2][i] + bb);
      }
      p += __shfl_xor(p, 16, 64);
      p += __shfl_xor(p, 32, 64);
      if (lane < 16)
        aggh[(size_t)e * 2064384 + (((bt * 32 + at) << 8) + c)] = (_Float16)p;
    }
  }
}

// ---------------- kernel C: output MLP 320->256->256->64 + residual ----------------
__global__ __launch_bounds__(256) void kc(
    const float* __restrict__ inputs, const unsigned short* __restrict__ AGG3,
    const unsigned short* __restrict__ O1T, const unsigned short* __restrict__ O2T,
    const unsigned short* __restrict__ O3T,
    const float* __restrict__ ob1, const float* __restrict__ ob2, const float* __restrict__ ob3,
    float* __restrict__ out) {
  int t = blockIdx.x, b = blockIdx.y;
  int bt = b * 63 + t;
  int tid = threadIdx.x, lane = tid & 63, wid = tid >> 6;
  int waveM = wid & 1, waveN = wid >> 1;
  __shared__ __align__(16) _Float16 aug[32 * 328];
  __shared__ __align__(16) _Float16 h1[32 * 264];
  __shared__ __align__(16) _Float16 h2[32 * 264];
  __shared__ __align__(16) _Float16 Bt[256 * 40];
  __shared__ __align__(16) float xs[32 * 64];
  __shared__ float lb1[256], lb2[256], lb3[64];
  {
    int a = tid >> 3, d0 = (tid & 7) * 8;
    const float* src = inputs + (((b * 32 + a) * 64 + t) << 6) + d0;
    float4 v0 = *(const float4*)src;
    float4 v1 = *(const float4*)(src + 4);
    *(float4*)&xs[a * 64 + d0] = v0;
    *(float4*)&xs[a * 64 + d0 + 4] = v1;
    uint4 w;
    w.x = pkh(v0.x, v0.y); w.y = pkh(v0.z, v0.w);
    w.z = pkh(v1.x, v1.y); w.w = pkh(v1.z, v1.w);
    *(uint4*)&aug[a * 328 + d0] = w;
  }
  #pragma unroll
  for (int qq = 0; qq < 4; ++qq) {
    int cid = tid + qq * 256;
    int a = cid >> 5, c8 = (cid & 31) * 8;
    size_t o = ((size_t)(bt * 32 + a) << 8) + c8;
    f16x8 v0 = *(const f16x8*)&AGG3[o];
    f16x8 v1 = *(const f16x8*)&AGG3[2064384 + o];
    f16x8 v2 = *(const f16x8*)&AGG3[4128768 + o];
    f16x8 s = v0 + v1 + v2;
    *(uint4*)&aug[a * 328 + 64 + c8] = __builtin_bit_cast(uint4, s);
  }
  lb1[tid] = ob1[tid];
  lb2[tid] = ob2[tid];
  if (tid < 64) lb3[tid] = ob3[tid];
  __syncthreads();
  f32x4 acc[8];
  #pragma unroll
  for (int f = 0; f < 8; ++f) acc[f] = f32x4{0.f, 0.f, 0.f, 0.f};
  for (int kk = 0; kk < 10; ++kk) {  // fc1: K=320
    #pragma unroll
    for (int q = 0; q < 4; ++q) {
      int cid = tid + q * 256;
      int n = cid >> 2, c8 = (cid & 3) * 8;
      *(uint4*)&Bt[n * 40 + c8] = *(const uint4*)&O1T[n * 320 + kk * 32 + c8];
    }
    __syncthreads();
    f16x8 av = *(const f16x8*)&aug[(waveM * 16 + (lane & 15)) * 328 + kk * 32 + (lane >> 4) * 8];
    #pragma unroll
    for (int f = 0; f < 8; ++f) {
      f16x8 bv = *(const f16x8*)&Bt[(waveN * 128 + f * 16 + (lane & 15)) * 40 + (lane >> 4) * 8];
      acc[f] = MFMAH(av, bv, acc[f]);
    }
    __syncthreads();
  }
  #pragma unroll
  for (int f = 0; f < 8; ++f) {
    int c = waveN * 128 + f * 16 + (lane & 15);
    #pragma unroll
    for (int i = 0; i < 4; ++i) {
      int r = waveM * 16 + (lane >> 4) * 4 + i;
      h1[r * 264 + c] = (_Float16)lrelu(acc[f][i] + lb1[c]);
    }
  }
  __syncthreads();
  #pragma unroll
  for (int f = 0; f < 8; ++f) acc[f] = f32x4{0.f, 0.f, 0.f, 0.f};
  for (int kk = 0; kk < 8; ++kk) {  // fc2: K=256
    #pragma unroll
    for (int q = 0; q < 4; ++q) {
      int cid = tid + q * 256;
      int n = cid >> 2, c8 = (cid & 3) * 8;
      *(uint4*)&Bt[n * 40 + c8] = *(const uint4*)&O2T[n * 256 + kk * 32 + c8];
    }
    __syncthreads();
    f16x8 av = *(const f16x8*)&h1[(waveM * 16 + (lane & 15)) * 264 + kk * 32 + (lane >> 4) * 8];
    #pragma unroll
    for (int f = 0; f < 8; ++f) {
      f16x8 bv = *(const f16x8*)&Bt[(waveN * 128 + f * 16 + (lane & 15)) * 40 + (lane >> 4) * 8];
      acc[f] = MFMAH(av, bv, acc[f]);
    }
    __syncthreads();
  }
  #pragma unroll
  for (int f = 0; f < 8; ++f) {
    int c = waveN * 128 + f * 16 + (lane & 15);
    #pragma unroll
    for (int i = 0; i < 4; ++i) {
      int r = waveM * 16 + (lane >> 4) * 4 + i;
      h2[r * 264 + c] = (_Float16)lrelu(acc[f][i] + lb2[c]);
    }
  }
  __syncthreads();
  f32x4 a3[2];
  a3[0] = f32x4{0.f, 0.f, 0.f, 0.f};
  a3[1] = f32x4{0.f, 0.f, 0.f, 0.f};
  for (int kk = 0; kk < 8; ++kk) {  // fc3: K=256, N=64
    {
      int n = tid >> 2, c8 = (tid & 3) * 8;
      *(uint4*)&Bt[n * 40 + c8] = *(const uint4*)&O3T[n * 256 + kk * 32 + c8];
    }
    __syncthreads();
    f16x8 av = *(const f16x8*)&h2[(waveM * 16 + (lane & 15)) * 264 + kk * 32 + (lane >> 4) * 8];
    #pragma unroll
    for (int f = 0; f < 2; ++f) {
      f16x8 bv = *(const f16x8*)&Bt[(waveN * 32 + f * 16 + (lane & 15)) * 40 + (lane >> 4) * 8];
      a3[f] = MFMAH(av, bv, a3[f]);
    }
    __syncthreads();
  }
  #pragma unroll
  for (int f = 0; f < 2; ++f) {
    int d = waveN * 32 + f * 16 + (lane & 15);
    #pragma unroll
    for (int i = 0; i < 4; ++i) {
      int a = waveM * 16 + (lane >> 4) * 4 + i;
      out[((b * 32 + a) * 63 + t) * 64 + d] = a3[f][i] + lb3[d] + xs[a * 64 + d];
    }
  }
}

extern "C" void kernel_launch(void* const* d_in, const int* in_sizes, int n_in,
                              void* d_out, int out_size, void* d_ws, size_t ws_size,
                              hipStream_t stream) {
  const float* inputs   = (const float*)d_in[0];
  const float* state    = (const float*)d_in[1];
  const float* rel_type = (const float*)d_in[2];
  const float* w1  = (const float*)d_in[5];
  const float* b1  = (const float*)d_in[6];
  const float* w2  = (const float*)d_in[7];
  const float* b2  = (const float*)d_in[8];
  const float* o1w = (const float*)d_in[9];
  const float* o1b = (const float*)d_in[10];
  const float* o2w = (const float*)d_in[11];
  const float* o2b = (const float*)d_in[12];
  const float* o3w = (const float*)d_in[13];
  const float* o3b = (const float*)d_in[14];
  char* ws = (char*)d_ws;
  unsigned short* W1T = (unsigned short*)(ws + 0);
  unsigned short* W2F = (unsigned short*)(ws + 196608);     // 393216 B (frag-linear)
  unsigned short* O1T = (unsigned short*)(ws + 589824);
  unsigned short* O2T = (unsigned short*)(ws + 753664);
  unsigned short* O3T = (unsigned short*)(ws + 884736);
  unsigned short* Pp  = (unsigned short*)(ws + 917504);     // 24772608 B
  float* G    = (float*)(ws + 25690112);                    // 3096576 B
  unsigned short* AGG3 = (unsigned short*)(ws + 28786688);  // 12386304 B
  float* out = (float*)d_out;

  kw<<<1792, 256, 0, stream>>>(w1, w2, o1w, o2w, o3w, W1T, W2F, O1T, O2T, O3T);
  ka<<<dim3(63, 4), 256, 0, stream>>>(inputs, state, rel_type, W1T, b1, Pp, G);
  kb<<<3024, 512, 0, stream>>>(Pp, G, W2F, b2, AGG3);
  kc<<<dim3(63, 4), 256, 0, stream>>>(inputs, AGG3, O1T, O2T, O3T, o1b, o2b, o3b, out);
}

// Round 10
// 173.682 us; speedup vs baseline: 1.1901x; 1.1901x over previous
//
#include <hip/hip_runtime.h>

// NRI MLP decoder, fused f16-MFMA pipeline, v27.
// B=4, T=64 (t<63 out), A=32, R=992 (=32 recv x 31 edges), D=64, S=4,
// E=4 (type 0 skipped), MH=MO=NH=256.
//
//   h1[b,t,r] = lrelu(PS[send(r)] + PRb[rec(r)])   (PRb has b1 folded, from ka)
//   msg = lrelu(h1 @ W2 + b2) ; agg[a] = sum_{r:rec=a} g[r]*msg[r]
// kb v27: B OFF THE LDS PIPE. Validated model (v18/v22/v26): per-CU time =
// MFMA_cy + LDS_cy + overhead (pipes fully serialized at every tried
// schedule/occupancy). v18: MFMA 49us + LDS 16.6MB/CU/85B-per-cy = 81us ->
// 130 ~= 135 measured. 9 of the 16.6MB is the B panel (gl16 writes 3MB + bv
// ds_reads 6MB). W2F is fragment-linear (built by kw), so a wave's bv frag
// is a perfectly coalesced 1KB per-lane GLOBAL load; W2F = 384KB = fully
// L2-resident and L1-hot (co-resident blocks share e). v27 loads bv
// global->VGPR, double-banked bvb[2][4] prefetched 1 step ahead (compiler
// emits the counted vmcnt automatically), and deletes the Bt ring + gl16.
// LDS keeps only h1 (dedup across waves -- v21/v23 proved A must stay).
// Geometry: 256-thr blocks (4 waves 1Mx4N), block = 64 rows x N256, grid
// 12096; launch_bounds(256,3) -> ~170-reg cap, 12 waves/CU (3 blocks).
// acc64 + bvb32 + af16 + P8 + addr ~= 140 regs. LDS/block 9.5KB.
// Model: per CU-step MFMA 930 + LDS 720 + ovh ~= 1900cy -> kb ~95-110us
// even if still fully serialized. Bit-identical math to v18.

typedef _Float16 f16x8 __attribute__((ext_vector_type(8)));
typedef float f32x4 __attribute__((ext_vector_type(4)));

#define MFMAH(a, b, c) __builtin_amdgcn_mfma_f32_16x16x32_f16((a), (b), (c), 0, 0, 0)

// full-drain barrier (__syncthreads semantics, explicit) — prologue only
#define KBAR0() do {                                             \
  __builtin_amdgcn_sched_barrier(0);                             \
  asm volatile("s_waitcnt vmcnt(0) lgkmcnt(0)" ::: "memory");    \
  __builtin_amdgcn_s_barrier();                                  \
  __builtin_amdgcn_sched_barrier(0);                             \
} while (0)

// LDS-only barrier: drains ds ops, leaves global loads in flight
#define KBARL() do {                                             \
  __builtin_amdgcn_sched_barrier(0);                             \
  asm volatile("s_waitcnt lgkmcnt(0)" ::: "memory");             \
  __builtin_amdgcn_s_barrier();                                  \
  __builtin_amdgcn_sched_barrier(0);                             \
} while (0)

__device__ __forceinline__ unsigned pkh(float lo, float hi) {
  auto h = __builtin_amdgcn_cvt_pkrtz(lo, hi);
  return __builtin_bit_cast(unsigned, h);
}
__device__ __forceinline__ unsigned short f2h(float f) {
  return __builtin_bit_cast(unsigned short, (_Float16)f);
}
__device__ __forceinline__ float lrelu(float x) { return x > 0.f ? x : 0.01f * x; }

// ---------------- kernel W: weight transpose + f16 convert ----------------
// W2F fragment-linear: [e][kstep 0..7][ntile 0..15][lane 0..63][j 0..7]
//   n = ntile*16 + (lane&15), k = kstep*32 + (lane>>4)*8 + j.
__global__ __launch_bounds__(256) void kw(
    const float* __restrict__ w1, const float* __restrict__ w2,
    const float* __restrict__ o1, const float* __restrict__ o2, const float* __restrict__ o3,
    unsigned short* __restrict__ W1T, unsigned short* __restrict__ W2F,
    unsigned short* __restrict__ O1T, unsigned short* __restrict__ O2T,
    unsigned short* __restrict__ O3T) {
  int i = blockIdx.x * 256 + threadIdx.x;
  if (i < 98304) {
    int k = i & 63, n = (i >> 6) & 255, eh = i >> 14;
    int e = (eh >> 1) + 1, half = eh & 1;
    W1T[i] = f2h(w1[(e * 128 + half * 64 + k) * 256 + n]);
    return;
  }
  i -= 98304;
  if (i < 196608) {
    int j = i & 7, l = (i >> 3) & 63, t = (i >> 9) & 15, s = (i >> 13) & 7, e = i >> 16;
    int n = t * 16 + (l & 15);
    int k = s * 32 + (l >> 4) * 8 + j;
    W2F[i] = f2h(w2[(e + 1) * 65536 + k * 256 + n]);
    return;
  }
  i -= 196608;
  if (i < 81920) {
    int k = i % 320, n = i / 320;
    O1T[i] = f2h(o1[k * 256 + n]);
    return;
  }
  i -= 81920;
  if (i < 65536) {
    int k = i & 255, n = i >> 8;
    O2T[i] = f2h(o2[k * 256 + n]);
    return;
  }
  i -= 65536;
  {
    int k = i & 255, n = i >> 8;
    O3T[i] = f2h(o3[k * 64 + n]);
  }
}

// ---------------- kernel A: per-atom projections P + gates G ----------------
__global__ __launch_bounds__(256) void ka(
    const float* __restrict__ inputs, const float* __restrict__ state,
    const float* __restrict__ rel_type, const unsigned short* __restrict__ W1T,
    const float* __restrict__ b1g,
    unsigned short* __restrict__ P, float* __restrict__ G) {
  int t = blockIdx.x, b = blockIdx.y;
  int bt = b * 63 + t;
  int tid = threadIdx.x, lane = tid & 63, wid = tid >> 6;
  int waveM = wid & 1, waveN = wid >> 1;
  __shared__ __align__(16) _Float16 xa[32 * 72];
  __shared__ __align__(16) _Float16 Bt[256 * 72];
  __shared__ __align__(16) _Float16 Ps[32 * 256];
  __shared__ float ss[32][4];
  {
    int a = tid >> 3, d0 = (tid & 7) * 8;
    const float* src = inputs + (((b * 32 + a) * 64 + t) << 6) + d0;
    float4 v0 = *(const float4*)src;
    float4 v1 = *(const float4*)(src + 4);
    uint4 w;
    w.x = pkh(v0.x, v0.y); w.y = pkh(v0.z, v0.w);
    w.z = pkh(v1.x, v1.y); w.w = pkh(v1.z, v1.w);
    *(uint4*)&xa[a * 72 + d0] = w;
  }
  if (tid < 128) {
    int a = tid >> 2, s = tid & 3;
    ss[a][s] = state[((b * 32 + a) * 64 + t) * 4 + s];
  }
  __syncthreads();
  #pragma unroll
  for (int q = 0; q < 12; ++q) {
    int task = tid + q * 256;
    int e = task >> 10, rem = task & 1023, a = rem >> 5, k = rem & 31;
    float g = 0.f;
    if (k < 31) {
      int sA = k + (k >= a ? 1 : 0);
      int r = a * 31 + k;
      const float* rt = rel_type + (b * 992 + r) * 16 + (e + 1);
      g = rt[0] * ss[sA][0] + rt[4] * ss[sA][1] + rt[8] * ss[sA][2] + rt[12] * ss[sA][3];
    }
    G[(bt * 3 + e) * 1024 + a * 32 + k] = g;
  }
  for (int eh = 0; eh < 6; ++eh) {
    #pragma unroll
    for (int q = 0; q < 8; ++q) {
      int cid = tid + q * 256;
      int n = cid >> 3, c8 = (cid & 7) * 8;
      *(uint4*)&Bt[n * 72 + c8] = *(const uint4*)&W1T[(eh * 256 + n) * 64 + c8];
    }
    __syncthreads();
    f32x4 acc[8];
    #pragma unroll
    for (int f = 0; f < 8; ++f) acc[f] = f32x4{0.f, 0.f, 0.f, 0.f};
    #pragma unroll
    for (int ik = 0; ik < 2; ++ik) {
      int k0 = ik * 32;
      f16x8 av = *(const f16x8*)&xa[(waveM * 16 + (lane & 15)) * 72 + k0 + (lane >> 4) * 8];
      #pragma unroll
      for (int f = 0; f < 8; ++f) {
        f16x8 bv = *(const f16x8*)&Bt[(waveN * 128 + f * 16 + (lane & 15)) * 72 + k0 + (lane >> 4) * 8];
        acc[f] = MFMAH(av, bv, acc[f]);
      }
    }
    #pragma unroll
    for (int f = 0; f < 8; ++f) {
      int c = waveN * 128 + f * 16 + (lane & 15);
      float bias = (eh & 1) ? b1g[((eh >> 1) + 1) * 256 + c] : 0.f;
      #pragma unroll
      for (int i = 0; i < 4; ++i) {
        int rrow = waveM * 16 + (lane >> 4) * 4 + i;
        Ps[rrow * 256 + c] = (_Float16)(acc[f][i] + bias);
      }
    }
    __syncthreads();
    unsigned short* dst = P + (bt * 6 + eh) * 8192;
    #pragma unroll
    for (int q = 0; q < 4; ++q) {
      int o = (tid + q * 256) * 8;
      *(uint4*)&dst[o] = *(const uint4*)&Ps[o];
    }
    __syncthreads();
  }
}

// ---------------- kernel B v27: bv from global regs, h1-only LDS ------------
// grid.x = 12096 = 8*1512; swz: q fastest, then bt, then e.
__global__ __launch_bounds__(256, 3) void kb(
    const unsigned short* __restrict__ P, const float* __restrict__ G,
    const unsigned short* __restrict__ W2F, const float* __restrict__ b2g,
    unsigned short* __restrict__ AGG3) {
  int bx = blockIdx.x;
  int swz = (bx & 7) * 1512 + (bx >> 3);
  int e = swz / 4032;
  int rem = swz - e * 4032;
  int bt = rem >> 4, q = rem & 15;           // q: 64-row chunk (2 atoms)
  int tid = threadIdx.x, lane = tid & 63, wid = tid >> 6;  // wid = waveN 0..3
  int lane15 = lane & 15, kqh = lane >> 4;   // 0..3

  __shared__ __align__(16) _Float16 h1F[2][2048];  // 2 x 4KB dbuf, frag-linear
  __shared__ float gs[64];
  __shared__ float b2s[256];
  // LDS total: 8192 + 256 + 1024 = 9472B. Residency reg-capped at 12 waves.

  const unsigned short* psrc  = P + (bt * 6 + e * 2) * 8192;  // PS slab (send)
  const unsigned short* prsrc = psrc + 8192;                   // PRb slab
  const unsigned short* w2f   = W2F + e * 65536;               // [step][ntile][lane][8]

  // h1 build: thread builds slot tid: Mtile wid, row r = wid*16+lane15, chunk kqh.
  int r = wid * 16 + lane15;
  int al0 = r >> 5, bk = r & 31;             // atom-in-block, edge slot
  int aG = q * 2 + al0;                      // global atom id
  int bs = (bk < 31) ? (bk + (bk >= aG ? 1 : 0)) : 0;  // k=31 pad (g=0)
  const unsigned short* pvg = psrc + bs * 256 + kqh * 8;
  const unsigned short* rvg = prsrc + aG * 256 + kqh * 8;
  int h1off = tid * 8;

  // bv global base: wave wid owns ntiles wid*4+g2; per-lane 16B, coalesced 1KB.
  const unsigned short* bvg = w2f + (wid * 4) * 512 + lane * 8;

  f16x8 bvb[2][4];  // double-banked B fragments (prefetched 1 step ahead)

  // ---- prologue: P(0), bv(0), gates/bias, build h1(0) ----
  {
    f16x8 pv = *(const f16x8*)pvg;
    f16x8 rv = *(const f16x8*)rvg;
    #pragma unroll
    for (int g2 = 0; g2 < 4; ++g2)
      bvb[0][g2] = *(const f16x8*)(bvg + g2 * 512);
    b2s[tid] = b2g[(e + 1) * 256 + tid];
    if (tid < 64) gs[tid] = G[((bt * 3 + e) << 10) + q * 64 + tid];
    f16x8 h = pv + rv;
    *(f16x8*)&h1F[0][h1off] = __builtin_elementwise_max(h, h * (_Float16)0.01f);
  }
  KBAR0();  // h1(0) + gs/b2s ready (bv/P waits are compiler-tracked anyway)

  f32x4 acc[4][4];
  #pragma unroll
  for (int f = 0; f < 4; ++f)
    #pragma unroll
    for (int g2 = 0; g2 < 4; ++g2) acc[f][g2] = f32x4{0.f, 0.f, 0.f, 0.f};

  #pragma unroll
  for (int s = 0; s < 8; ++s) {
    const int cb = s & 1;
    // issue P(s+1) first (oldest vmem of the step)...
    f16x8 pv, rv;
    if (s < 7) {
      pv = *(const f16x8*)(pvg + (s + 1) * 32);
      rv = *(const f16x8*)(rvg + (s + 1) * 32);
    }
    __builtin_amdgcn_sched_barrier(0);
    // ...then bv(s+1) into the other bank (newest; lands during MFMA/build;
    // compiler emits the counted vmcnt before next step's first MFMA use)
    if (s < 7) {
      #pragma unroll
      for (int g2 = 0; g2 < 4; ++g2)
        bvb[cb ^ 1][g2] = *(const f16x8*)(bvg + (s + 1) * 8192 + g2 * 512);
    }
    __builtin_amdgcn_sched_barrier(0);
    // af reads (the only per-step LDS reads) + MFMA on register B
    f16x8 af[4];
    #pragma unroll
    for (int f = 0; f < 4; ++f)
      af[f] = *(const f16x8*)&h1F[cb][f * 512 + lane * 8];
    __builtin_amdgcn_s_setprio(1);
    #pragma unroll
    for (int g2 = 0; g2 < 4; ++g2)
      #pragma unroll
      for (int f = 0; f < 4; ++f)
        acc[f][g2] = MFMAH(af[f], bvb[cb][g2], acc[f][g2]);
    __builtin_amdgcn_s_setprio(0);
    if (s < 7) {
      // build h1(s+1): compiler waits vmcnt(4) here (pv/rv; 4 bv loads newer)
      f16x8 h = pv + rv;
      *(f16x8*)&h1F[cb ^ 1][h1off] = __builtin_elementwise_max(h, h * (_Float16)0.01f);
      KBARL();  // lgkm-only: h1 dbuf handoff; bv loads stay in flight
    }
  }

  // epilogue: p(al,c) = sum_k g[k]*lrelu(acc+b2); write f16 partial per type.
  // acc[f][g2][i]: row r = f*16 + kqh*4 + i -> atom f>>1, k = (f&1)*16+kqh*4+i.
  _Float16* aggh = (_Float16*)AGG3;
  #pragma unroll
  for (int al = 0; al < 2; ++al) {
    #pragma unroll
    for (int g2 = 0; g2 < 4; ++g2) {
      int c = wid * 64 + g2 * 16 + lane15;
      float bb = b2s[c];
      float p = 0.f;
      #pragma unroll
      for (int fh = 0; fh < 2; ++fh) {
        int f = al * 2 + fh;
        int k4 = fh * 16 + kqh * 4;
        #pragma unroll
        for (int i = 0; i < 4; ++i)
          p += gs[al * 32 + k4 + i] * lrelu(acc[f][g2][i] + bb);
      }
      p += __shfl_xor(p, 16, 64);
      p += __shfl_xor(p, 32, 64);
      if (lane < 16)
        aggh[(size_t)e * 2064384 + (((bt * 32 + q * 2 + al) << 8) + c)] = (_Float16)p;
    }
  }
}

// ---------------- kernel C: output MLP 320->256->256->64 + residual ----------------
__global__ __launch_bounds__(256) void kc(
    const float* __restrict__ inputs, const unsigned short* __restrict__ AGG3,
    const unsigned short* __restrict__ O1T, const unsigned short* __restrict__ O2T,
    const unsigned short* __restrict__ O3T,
    const float* __restrict__ ob1, const float* __restrict__ ob2, const float* __restrict__ ob3,
    float* __restrict__ out) {
  int t = blockIdx.x, b = blockIdx.y;
  int bt = b * 63 + t;
  int tid = threadIdx.x, lane = tid & 63, wid = tid >> 6;
  int waveM = wid & 1, waveN = wid >> 1;
  __shared__ __align__(16) _Float16 aug[32 * 328];
  __shared__ __align__(16) _Float16 h1[32 * 264];
  __shared__ __align__(16) _Float16 h2[32 * 264];
  __shared__ __align__(16) _Float16 Bt[256 * 40];
  __shared__ __align__(16) float xs[32 * 64];
  __shared__ float lb1[256], lb2[256], lb3[64];
  {
    int a = tid >> 3, d0 = (tid & 7) * 8;
    const float* src = inputs + (((b * 32 + a) * 64 + t) << 6) + d0;
    float4 v0 = *(const float4*)src;
    float4 v1 = *(const float4*)(src + 4);
    *(float4*)&xs[a * 64 + d0] = v0;
    *(float4*)&xs[a * 64 + d0 + 4] = v1;
    uint4 w;
    w.x = pkh(v0.x, v0.y); w.y = pkh(v0.z, v0.w);
    w.z = pkh(v1.x, v1.y); w.w = pkh(v1.z, v1.w);
    *(uint4*)&aug[a * 328 + d0] = w;
  }
  #pragma unroll
  for (int qq = 0; qq < 4; ++qq) {
    int cid = tid + qq * 256;
    int a = cid >> 5, c8 = (cid & 31) * 8;
    size_t o = ((size_t)(bt * 32 + a) << 8) + c8;
    f16x8 v0 = *(const f16x8*)&AGG3[o];
    f16x8 v1 = *(const f16x8*)&AGG3[2064384 + o];
    f16x8 v2 = *(const f16x8*)&AGG3[4128768 + o];
    f16x8 s = v0 + v1 + v2;
    *(uint4*)&aug[a * 328 + 64 + c8] = __builtin_bit_cast(uint4, s);
  }
  lb1[tid] = ob1[tid];
  lb2[tid] = ob2[tid];
  if (tid < 64) lb3[tid] = ob3[tid];
  __syncthreads();
  f32x4 acc[8];
  #pragma unroll
  for (int f = 0; f < 8; ++f) acc[f] = f32x4{0.f, 0.f, 0.f, 0.f};
  for (int kk = 0; kk < 10; ++kk) {  // fc1: K=320
    #pragma unroll
    for (int q = 0; q < 4; ++q) {
      int cid = tid + q * 256;
      int n = cid >> 2, c8 = (cid & 3) * 8;
      *(uint4*)&Bt[n * 40 + c8] = *(const uint4*)&O1T[n * 320 + kk * 32 + c8];
    }
    __syncthreads();
    f16x8 av = *(const f16x8*)&aug[(waveM * 16 + (lane & 15)) * 328 + kk * 32 + (lane >> 4) * 8];
    #pragma unroll
    for (int f = 0; f < 8; ++f) {
      f16x8 bv = *(const f16x8*)&Bt[(waveN * 128 + f * 16 + (lane & 15)) * 40 + (lane >> 4) * 8];
      acc[f] = MFMAH(av, bv, acc[f]);
    }
    __syncthreads();
  }
  #pragma unroll
  for (int f = 0; f < 8; ++f) {
    int c = waveN * 128 + f * 16 + (lane & 15);
    #pragma unroll
    for (int i = 0; i < 4; ++i) {
      int r = waveM * 16 + (lane >> 4) * 4 + i;
      h1[r * 264 + c] = (_Float16)lrelu(acc[f][i] + lb1[c]);
    }
  }
  __syncthreads();
  #pragma unroll
  for (int f = 0; f < 8; ++f) acc[f] = f32x4{0.f, 0.f, 0.f, 0.f};
  for (int kk = 0; kk < 8; ++kk) {  // fc2: K=256
    #pragma unroll
    for (int q = 0; q < 4; ++q) {
      int cid = tid + q * 256;
      int n = cid >> 2, c8 = (cid & 3) * 8;
      *(uint4*)&Bt[n * 40 + c8] = *(const uint4*)&O2T[n * 256 + kk * 32 + c8];
    }
    __syncthreads();
    f16x8 av = *(const f16x8*)&h1[(waveM * 16 + (lane & 15)) * 264 + kk * 32 + (lane >> 4) * 8];
    #pragma unroll
    for (int f = 0; f < 8; ++f) {
      f16x8 bv = *(const f16x8*)&Bt[(waveN * 128 + f * 16 + (lane & 15)) * 40 + (lane >> 4) * 8];
      acc[f] = MFMAH(av, bv, acc[f]);
    }
    __syncthreads();
  }
  #pragma unroll
  for (int f = 0; f < 8; ++f) {
    int c = waveN * 128 + f * 16 + (lane & 15);
    #pragma unroll
    for (int i = 0; i < 4; ++i) {
      int r = waveM * 16 + (lane >> 4) * 4 + i;
      h2[r * 264 + c] = (_Float16)lrelu(acc[f][i] + lb2[c]);
    }
  }
  __syncthreads();
  f32x4 a3[2];
  a3[0] = f32x4{0.f, 0.f, 0.f, 0.f};
  a3[1] = f32x4{0.f, 0.f, 0.f, 0.f};
  for (int kk = 0; kk < 8; ++kk) {  // fc3: K=256, N=64
    {
      int n = tid >> 2, c8 = (tid & 3) * 8;
      *(uint4*)&Bt[n * 40 + c8] = *(const uint4*)&O3T[n * 256 + kk * 32 + c8];
    }
    __syncthreads();
    f16x8 av = *(const f16x8*)&h2[(waveM * 16 + (lane & 15)) * 264 + kk * 32 + (lane >> 4) * 8];
    #pragma unroll
    for (int f = 0; f < 2; ++f) {
      f16x8 bv = *(const f16x8*)&Bt[(waveN * 32 + f * 16 + (lane & 15)) * 40 + (lane >> 4) * 8];
      a3[f] = MFMAH(av, bv, a3[f]);
    }
    __syncthreads();
  }
  #pragma unroll
  for (int f = 0; f < 2; ++f) {
    int d = waveN * 32 + f * 16 + (lane & 15);
    #pragma unroll
    for (int i = 0; i < 4; ++i) {
      int a = waveM * 16 + (lane >> 4) * 4 + i;
      out[((b * 32 + a) * 63 + t) * 64 + d] = a3[f][i] + lb3[d] + xs[a * 64 + d];
    }
  }
}

extern "C" void kernel_launch(void* const* d_in, const int* in_sizes, int n_in,
                              void* d_out, int out_size, void* d_ws, size_t ws_size,
                              hipStream_t stream) {
  const float* inputs   = (const float*)d_in[0];
  const float* state    = (const float*)d_in[1];
  const float* rel_type = (const float*)d_in[2];
  const float* w1  = (const float*)d_in[5];
  const float* b1  = (const float*)d_in[6];
  const float* w2  = (const float*)d_in[7];
  const float* b2  = (const float*)d_in[8];
  const float* o1w = (const float*)d_in[9];
  const float* o1b = (const float*)d_in[10];
  const float* o2w = (const float*)d_in[11];
  const float* o2b = (const float*)d_in[12];
  const float* o3w = (const float*)d_in[13];
  const float* o3b = (const float*)d_in[14];
  char* ws = (char*)d_ws;
  unsigned short* W1T = (unsigned short*)(ws + 0);
  unsigned short* W2F = (unsigned short*)(ws + 196608);     // 393216 B (frag-linear)
  unsigned short* O1T = (unsigned short*)(ws + 589824);
  unsigned short* O2T = (unsigned short*)(ws + 753664);
  unsigned short* O3T = (unsigned short*)(ws + 884736);
  unsigned short* Pp  = (unsigned short*)(ws + 917504);     // 24772608 B
  float* G    = (float*)(ws + 25690112);                    // 3096576 B
  unsigned short* AGG3 = (unsigned short*)(ws + 28786688);  // 12386304 B
  float* out = (float*)d_out;

  kw<<<1792, 256, 0, stream>>>(w1, w2, o1w, o2w, o3w, W1T, W2F, O1T, O2T, O3T);
  ka<<<dim3(63, 4), 256, 0, stream>>>(inputs, state, rel_type, W1T, b1, Pp, G);
  kb<<<12096, 256, 0, stream>>>(Pp, G, W2F, b2, AGG3);
  kc<<<dim3(63, 4), 256, 0, stream>>>(inputs, AGG3, O1T, O2T, O3T, o1b, o2b, o3b, out);
}